// Round 1
// baseline (1483.907 us; speedup 1.0000x reference)
//
#include <hip/hip_runtime.h>

// GraphLinear: out[b,n,o] = sum_m g[n,m] * (sum_i input[b,m,i]*W[type[m],o,i]) + bias[o]
// B=16384, N=128, DIN=DOUT=64, T=16. Fused two-stage MFMA kernel, bf16 compute / f32 accum.

#define NN   128
#define DI   64
#define DOUT 64
#define BT   16   // b-rows per workgroup (one per wave)
#define MC   32   // m-chunk size (K of stage-2 MFMA)

typedef __attribute__((ext_vector_type(4))) float f32x4;
typedef __attribute__((ext_vector_type(8))) short bf16x8;

__device__ __forceinline__ short f2bf(float f) {
    unsigned u = __builtin_bit_cast(unsigned, f);
    u += 0x7FFFu + ((u >> 16) & 1u);   // round-to-nearest-even
    return (short)(u >> 16);
}

__device__ __forceinline__ bf16x8 load8cvt(const float* __restrict__ p) {
    const f32x4 a = *(const f32x4*)p;
    const f32x4 b = *(const f32x4*)(p + 4);
    bf16x8 r;
    r[0] = f2bf(a[0]); r[1] = f2bf(a[1]); r[2] = f2bf(a[2]); r[3] = f2bf(a[3]);
    r[4] = f2bf(b[0]); r[5] = f2bf(b[1]); r[6] = f2bf(b[2]); r[7] = f2bf(b[3]);
    return r;
}

__global__ __launch_bounds__(1024, 8)
void graph_linear_fused(const float* __restrict__ input,   // [B,128,64]
                        const float* __restrict__ g,       // [128,128]
                        const float* __restrict__ weight,  // [16,64,64]
                        const float* __restrict__ bias,    // [64]
                        const int*   __restrict__ ntype,   // [128]
                        float* __restrict__ out)           // [B,128,64]
{
    // h chunk: [b=16][o=64][m=32] bf16, 64 KiB. XOR swizzle on m (16B granular)
    // so stage-2 ds_read_b128 spreads across banks.
    __shared__ short hbuf[BT * DOUT * MC];

    const int tid  = threadIdx.x;
    const int lane = tid & 63;
    const int wave = tid >> 6;     // 0..15
    const int lo   = lane & 15;
    const int hi   = lane >> 4;    // 0..3
    const int b0   = blockIdx.x * BT;

    f32x4 acc[8][4];               // [n-tile][o-tile] -> 128 VGPRs
#pragma unroll
    for (int nt = 0; nt < 8; ++nt)
#pragma unroll
        for (int ot = 0; ot < 4; ++ot)
            acc[nt][ot] = 0.0f;

    for (int c = 0; c < 4; ++c) {
        // ---------------- stage 1: h[b, m-chunk, o] ----------------
        // wave handles m = c*32 + wave*2 + {0,1}; MFMA M=b(16) N=o(16x4) K=i(32x2)
#pragma unroll
        for (int mm = 0; mm < 2; ++mm) {
            const int mloc = wave * 2 + mm;
            const int m    = c * MC + mloc;
            const int t    = __ldg(&ntype[m]);
            const float* wrow = weight + t * (DOUT * DI);
            const float* irow = input + ((b0 + lo) * NN + m) * DI;  // lane's b-row = lo

            const bf16x8 afr0 = load8cvt(irow + hi * 8);          // k = 0..31
            const bf16x8 afr1 = load8cvt(irow + 32 + hi * 8);     // k = 32..63

            f32x4 hacc[4];
#pragma unroll
            for (int ot = 0; ot < 4; ++ot) hacc[ot] = 0.0f;
#pragma unroll
            for (int ot = 0; ot < 4; ++ot) {
                const int o = ot * 16 + lo;                       // B-frag col = o
                const bf16x8 w0 = load8cvt(wrow + o * DI + hi * 8);
                hacc[ot] = __builtin_amdgcn_mfma_f32_16x16x32_bf16(afr0, w0, hacc[ot], 0, 0, 0);
                const bf16x8 w1 = load8cvt(wrow + o * DI + 32 + hi * 8);
                hacc[ot] = __builtin_amdgcn_mfma_f32_16x16x32_bf16(afr1, w1, hacc[ot], 0, 0, 0);
            }
            // D layout: col(o) = lane&15, row(b) = (lane>>4)*4 + j
#pragma unroll
            for (int ot = 0; ot < 4; ++ot) {
                const int o   = ot * 16 + lo;
                const int msw = mloc ^ ((o & 3) << 3);
#pragma unroll
                for (int j = 0; j < 4; ++j) {
                    const int bb = hi * 4 + j;
                    hbuf[(bb * DOUT + o) * MC + msw] = f2bf(hacc[ot][j]);
                }
            }
        }
        __syncthreads();

        // ---------------- stage 2: acc[n,o] += g[n, m-chunk] @ h[b=wave] ----------------
        bf16x8 hfr[4];
#pragma unroll
        for (int ot = 0; ot < 4; ++ot) {
            const int o   = ot * 16 + lo;                          // B-frag col = o
            const int idx = (wave * DOUT + o) * MC + ((hi * 8) ^ ((o & 3) << 3));
            hfr[ot] = *(const bf16x8*)&hbuf[idx];                  // 8 consecutive m (16B)
        }
#pragma unroll
        for (int nt = 0; nt < 8; ++nt) {
            const int n = nt * 16 + lo;                            // A-frag row = n
            const bf16x8 gfr = load8cvt(g + n * NN + c * MC + hi * 8);
#pragma unroll
            for (int ot = 0; ot < 4; ++ot)
                acc[nt][ot] = __builtin_amdgcn_mfma_f32_16x16x32_bf16(gfr, hfr[ot], acc[nt][ot], 0, 0, 0);
        }
        __syncthreads();
    }

    // ---------------- epilogue: out[b=b0+wave, n, o] = acc + bias ----------------
    const int b = b0 + wave;
#pragma unroll
    for (int ot = 0; ot < 4; ++ot) {
        const int o  = ot * 16 + lo;
        const float bv = __ldg(&bias[o]);
#pragma unroll
        for (int nt = 0; nt < 8; ++nt) {
#pragma unroll
            for (int j = 0; j < 4; ++j) {
                const int n = nt * 16 + hi * 4 + j;
                out[(b * NN + n) * DOUT + o] = acc[nt][ot][j] + bv;
            }
        }
    }
}

extern "C" void kernel_launch(void* const* d_in, const int* in_sizes, int n_in,
                              void* d_out, int out_size, void* d_ws, size_t ws_size,
                              hipStream_t stream) {
    const float* input  = (const float*)d_in[0];
    const float* g      = (const float*)d_in[1];
    const float* weight = (const float*)d_in[2];
    const float* bias   = (const float*)d_in[3];
    const int*   ntype  = (const int*)d_in[4];
    float* out = (float*)d_out;

    const int B = in_sizes[0] / (NN * DI);   // 16384
    dim3 grid(B / BT);
    dim3 block(1024);
    hipLaunchKernelGGL(graph_linear_fused, grid, block, 0, stream,
                       input, g, weight, bias, ntype, out);
}

// Round 2
// 454.592 us; speedup vs baseline: 3.2643x; 3.2643x over previous
//
#include <hip/hip_runtime.h>

// GraphLinear: out[b,n,o] = sum_m g[n,m] * (sum_i input[b,m,i]*W[type[m],o,i]) + bias[o]
// B=16384, N=128, DIN=DOUT=64, T=16.
// Kernel 1 (prep): convert weight/g to bf16 device globals; build type-sorted m-groups.
// Kernel 2 (main): BT=4 b-rows/block, 256 threads (4 waves).
//   Stage 1: type-grouped MFMA (4 m x 4 b = 16 rows share one W[t]) -> h in LDS (bf16, swizzled).
//   Stage 2: per-wave b, stream 8 n-tiles, K=128 from LDS, 16 acc regs live.

#define NN   128
#define DI   64
#define DOUT 64
#define BT   4
#define TT   16
#define MAXG 64

typedef __attribute__((ext_vector_type(4))) float f32x4;
typedef __attribute__((ext_vector_type(8))) short bf16x8;

__device__ __forceinline__ short f2bf(float f) {
    unsigned u = __builtin_bit_cast(unsigned, f);
    u += 0x7FFFu + ((u >> 16) & 1u);   // round-to-nearest-even
    return (short)(u >> 16);
}

__device__ __forceinline__ bf16x8 load8cvt(const float* __restrict__ p) {
    const f32x4 a = *(const f32x4*)p;
    const f32x4 b = *(const f32x4*)(p + 4);
    bf16x8 r;
    r[0] = f2bf(a[0]); r[1] = f2bf(a[1]); r[2] = f2bf(a[2]); r[3] = f2bf(a[3]);
    r[4] = f2bf(b[0]); r[5] = f2bf(b[1]); r[6] = f2bf(b[2]); r[7] = f2bf(b[3]);
    return r;
}

// Device-global scratch (rewritten every launch by prep_kernel; deterministic).
__device__ short d_wb[TT * DOUT * DI];        // bf16 weight [t][o][i], 128 KB
__device__ short d_gb[NN * NN];               // bf16 g [n][m], 32 KB
__device__ int   d_groups[1 + MAXG + MAXG*4]; // [G, gtype[64], gm[64][4] (-1 = pad)]

__global__ void prep_kernel(const float* __restrict__ weight,
                            const float* __restrict__ g,
                            const int*   __restrict__ ntype) {
    const int tid    = blockIdx.x * blockDim.x + threadIdx.x;
    const int stride = gridDim.x * blockDim.x;
    for (int i = tid; i < TT * DOUT * DI; i += stride) d_wb[i] = f2bf(weight[i]);
    for (int i = tid; i < NN * NN; i += stride)        d_gb[i] = f2bf(g[i]);
    if (tid == 0) {
        int G = 0;
        for (int t = 0; t < TT; ++t) {
            int mbuf[4]; int cur = 0;
            for (int m = 0; m < NN; ++m) {
                if (ntype[m] == t) {
                    mbuf[cur++] = m;
                    if (cur == 4) {
                        d_groups[1 + G] = t;
                        for (int k = 0; k < 4; ++k) d_groups[1 + MAXG + G*4 + k] = mbuf[k];
                        ++G; cur = 0;
                    }
                }
            }
            if (cur > 0) {
                d_groups[1 + G] = t;
                for (int k = 0; k < 4; ++k)
                    d_groups[1 + MAXG + G*4 + k] = (k < cur) ? mbuf[k] : -1;
                ++G;
            }
        }
        d_groups[0] = G;   // 32 <= G <= 48
    }
}

__global__ __launch_bounds__(256, 2)
void graph_linear_main(const float* __restrict__ input,   // [B,128,64] f32
                       const float* __restrict__ bias,    // [64] f32
                       float* __restrict__ out)           // [B,128,64] f32
{
    // h: [b=4][o=64][m=128] bf16 = 64 KiB; m index XOR-swizzled by ((o&7)<<3)
    // so stage-2 ds_read_b128 and stage-1 ds_write_b16 spread across banks.
    __shared__ short hbuf[BT * DOUT * NN];

    const int tid  = threadIdx.x;
    const int lane = tid & 63;
    const int wave = tid >> 6;        // 0..3
    const int lo   = lane & 15;
    const int hi   = lane >> 4;       // 0..3
    const int b0   = blockIdx.x * BT;

    // ---------------- stage 1: h[b, m, o] via type-grouped MFMA ----------------
    // Group = 4 same-type m's. A rows: r = (m_idx<<2) | b_idx  (16 rows, all valid).
    const int G  = d_groups[0];
    const int Gq = (G + 3) >> 2;
    const int g_beg = wave * Gq;
    const int g_end = (g_beg + Gq < G) ? (g_beg + Gq) : G;

    for (int gi = g_beg; gi < g_end; ++gi) {
        const int t  = d_groups[1 + gi];
        const int mA = d_groups[1 + MAXG + gi*4 + (lo >> 2)];  // this lane's A-row m
        const int mS = d_groups[1 + MAXG + gi*4 + hi];         // this lane's store m
        const int mAe = (mA < 0) ? 0 : mA;
        const float* irow = input + ((b0 + (lo & 3)) * NN + mAe) * DI;
        const bf16x8 a0 = load8cvt(irow + hi * 8);        // k = 0..31
        const bf16x8 a1 = load8cvt(irow + 32 + hi * 8);   // k = 32..63

        const short* wrow = d_wb + t * (DOUT * DI);
        f32x4 hacc[4];
#pragma unroll
        for (int ot = 0; ot < 4; ++ot) hacc[ot] = 0.0f;
#pragma unroll
        for (int ot = 0; ot < 4; ++ot) {
            const int o = ot * 16 + lo;                   // B-frag col
            const bf16x8 w0 = *(const bf16x8*)(wrow + o * DI + hi * 8);
            hacc[ot] = __builtin_amdgcn_mfma_f32_16x16x32_bf16(a0, w0, hacc[ot], 0, 0, 0);
            const bf16x8 w1 = *(const bf16x8*)(wrow + o * DI + 32 + hi * 8);
            hacc[ot] = __builtin_amdgcn_mfma_f32_16x16x32_bf16(a1, w1, hacc[ot], 0, 0, 0);
        }
        // D: col(o) = lane&15, row r = hi*4+j -> m_idx = hi, b = j
        if (mS >= 0) {
#pragma unroll
            for (int ot = 0; ot < 4; ++ot) {
                const int o   = ot * 16 + lo;
                const int msw = mS ^ ((o & 7) << 3);
#pragma unroll
                for (int j = 0; j < 4; ++j)
                    hbuf[(j * DOUT + o) * NN + msw] = f2bf(hacc[ot][j]);
            }
        }
    }
    __syncthreads();

    // ---------------- stage 2: out[b=wave, n, o] = g @ h + bias ----------------
    bf16x8 hfr[4][4];   // [k-chunk c][o-tile], 64 VGPRs, reused across all 8 n-tiles
#pragma unroll
    for (int c = 0; c < 4; ++c)
#pragma unroll
        for (int ot = 0; ot < 4; ++ot) {
            const int o  = ot * 16 + lo;
            const int m0 = (c * 32 + hi * 8) ^ ((o & 7) << 3);
            hfr[c][ot] = *(const bf16x8*)&hbuf[(wave * DOUT + o) * NN + m0];
        }
    float bv[4];
#pragma unroll
    for (int ot = 0; ot < 4; ++ot) bv[ot] = bias[ot * 16 + lo];

    const int bO = (b0 + wave) * NN;
#pragma unroll
    for (int nt = 0; nt < 8; ++nt) {
        const int n = nt * 16 + lo;                       // A-frag row
        bf16x8 gfr[4];
#pragma unroll
        for (int c = 0; c < 4; ++c)
            gfr[c] = *(const bf16x8*)(d_gb + n * NN + c * 32 + hi * 8);
        f32x4 acc[4];
#pragma unroll
        for (int ot = 0; ot < 4; ++ot) acc[ot] = 0.0f;
#pragma unroll
        for (int c = 0; c < 4; ++c)
#pragma unroll
            for (int ot = 0; ot < 4; ++ot)
                acc[ot] = __builtin_amdgcn_mfma_f32_16x16x32_bf16(gfr[c], hfr[c][ot], acc[ot], 0, 0, 0);
#pragma unroll
        for (int ot = 0; ot < 4; ++ot) {
            const int o = ot * 16 + lo;
#pragma unroll
            for (int j = 0; j < 4; ++j) {
                const int nn = nt * 16 + hi * 4 + j;
                out[(bO + nn) * DOUT + o] = acc[ot][j] + bv[ot];
            }
        }
    }
}

extern "C" void kernel_launch(void* const* d_in, const int* in_sizes, int n_in,
                              void* d_out, int out_size, void* d_ws, size_t ws_size,
                              hipStream_t stream) {
    const float* input  = (const float*)d_in[0];
    const float* g      = (const float*)d_in[1];
    const float* weight = (const float*)d_in[2];
    const float* bias   = (const float*)d_in[3];
    const int*   ntype  = (const int*)d_in[4];
    float* out = (float*)d_out;

    const int B = in_sizes[0] / (NN * DI);   // 16384

    hipLaunchKernelGGL(prep_kernel, dim3(32), dim3(256), 0, stream, weight, g, ntype);
    hipLaunchKernelGGL(graph_linear_main, dim3(B / BT), dim3(256), 0, stream,
                       input, bias, out);
}